// Round 1
// baseline (1848.214 us; speedup 1.0000x reference)
//
#include <hip/hip_runtime.h>

#define SH 68            // padded LDS row stride (floats): 68*4=272B, 16B-aligned, breaks bank conflicts
#define DT_C 0.1f

// ---- 4x4-block 64-K matmul helpers (A stride SH, B stride sb; acc += A[n0..][*] * B[*][e0..]) ----
__device__ __forceinline__ void mm16(const float* __restrict__ A,
                                     const float* __restrict__ B, int sb,
                                     float acc[4][4], int n0, int e0) {
  #pragma unroll 2
  for (int k = 0; k < 64; ++k) {
    float a0 = A[(n0+0)*SH+k];
    float a1 = A[(n0+1)*SH+k];
    float a2 = A[(n0+2)*SH+k];
    float a3 = A[(n0+3)*SH+k];
    const float4 bv = *(const float4*)(B + k*sb + e0);
    acc[0][0]+=a0*bv.x; acc[0][1]+=a0*bv.y; acc[0][2]+=a0*bv.z; acc[0][3]+=a0*bv.w;
    acc[1][0]+=a1*bv.x; acc[1][1]+=a1*bv.y; acc[1][2]+=a1*bv.z; acc[1][3]+=a1*bv.w;
    acc[2][0]+=a2*bv.x; acc[2][1]+=a2*bv.y; acc[2][2]+=a2*bv.z; acc[2][3]+=a2*bv.w;
    acc[3][0]+=a3*bv.x; acc[3][1]+=a3*bv.y; acc[3][2]+=a3*bv.z; acc[3][3]+=a3*bv.w;
  }
}

__device__ __forceinline__ void mm8(const float* __restrict__ A,
                                    const float* __restrict__ B, int sb,
                                    float acc[2][4], int n0, int e0) {
  #pragma unroll 4
  for (int k = 0; k < 64; ++k) {
    float a0 = A[(n0+0)*SH+k];
    float a1 = A[(n0+1)*SH+k];
    const float4 bv = *(const float4*)(B + k*sb + e0);
    acc[0][0]+=a0*bv.x; acc[0][1]+=a0*bv.y; acc[0][2]+=a0*bv.z; acc[0][3]+=a0*bv.w;
    acc[1][0]+=a1*bv.x; acc[1][1]+=a1*bv.y; acc[1][2]+=a1*bv.z; acc[1][3]+=a1*bv.w;
  }
}

// ---- conv1: [512,3,64,64] -> [512,32,32,32], k3 s2 p1, relu ----
__global__ __launch_bounds__(256) void conv1_k(const float* __restrict__ frames,
                                               const float* __restrict__ W,
                                               const float* __restrict__ bias,
                                               float* __restrict__ out) {
  __shared__ __align__(16) float sIn[12288];
  int bt = blockIdx.x, tid = threadIdx.x;
  const float4* src = (const float4*)(frames + (size_t)bt * 12288);
  for (int i = tid; i < 3072; i += 256) ((float4*)sIn)[i] = src[i];
  __syncthreads();
  for (int p = tid; p < 1024; p += 256) {
    int ho = p >> 5, wo = p & 31, hi0 = ho*2-1, wi0 = wo*2-1;
    for (int ocb = 0; ocb < 4; ++ocb) {
      float acc[8];
      #pragma unroll
      for (int j = 0; j < 8; ++j) acc[j] = bias[ocb*8+j];
      for (int ic = 0; ic < 3; ++ic) {
        float win[9];
        #pragma unroll
        for (int kh = 0; kh < 3; ++kh) {
          int hi = hi0 + kh;
          #pragma unroll
          for (int kw = 0; kw < 3; ++kw) {
            int wi = wi0 + kw;
            win[kh*3+kw] = (hi>=0 && hi<64 && wi>=0 && wi<64) ? sIn[ic*4096 + hi*64 + wi] : 0.f;
          }
        }
        #pragma unroll
        for (int j = 0; j < 8; ++j) {
          const float* wp = W + (size_t)(ocb*8+j)*27 + ic*9;  // uniform -> s_load
          #pragma unroll
          for (int k = 0; k < 9; ++k) acc[j] += win[k] * wp[k];
        }
      }
      #pragma unroll
      for (int j = 0; j < 8; ++j)
        out[(size_t)(bt*32 + ocb*8 + j)*1024 + p] = fmaxf(acc[j], 0.f);
    }
  }
}

// ---- conv2: [512,32,32,32] -> [512,64,16,16] ----
__global__ __launch_bounds__(256) void conv2_k(const float* __restrict__ in,
                                               const float* __restrict__ W,
                                               const float* __restrict__ bias,
                                               float* __restrict__ out) {
  __shared__ __align__(16) float sIn[32768];   // 128 KB
  int bt = blockIdx.x, tid = threadIdx.x;
  const float4* src = (const float4*)(in + (size_t)bt * 32768);
  for (int i = tid; i < 8192; i += 256) ((float4*)sIn)[i] = src[i];
  __syncthreads();
  int ho = tid >> 4, wo = tid & 15, hi0 = ho*2-1, wi0 = wo*2-1;
  for (int ocb = 0; ocb < 8; ++ocb) {
    float acc[8];
    #pragma unroll
    for (int j = 0; j < 8; ++j) acc[j] = bias[ocb*8+j];
    for (int ic = 0; ic < 32; ++ic) {
      float win[9];
      #pragma unroll
      for (int kh = 0; kh < 3; ++kh) {
        int hi = hi0 + kh;
        #pragma unroll
        for (int kw = 0; kw < 3; ++kw) {
          int wi = wi0 + kw;
          win[kh*3+kw] = (hi>=0 && hi<32 && wi>=0 && wi<32) ? sIn[ic*1024 + hi*32 + wi] : 0.f;
        }
      }
      #pragma unroll
      for (int j = 0; j < 8; ++j) {
        const float* wp = W + (size_t)(ocb*8+j)*288 + ic*9;
        #pragma unroll
        for (int k = 0; k < 9; ++k) acc[j] += win[k] * wp[k];
      }
    }
    #pragma unroll
    for (int j = 0; j < 8; ++j)
      out[(size_t)(bt*64 + ocb*8 + j)*256 + tid] = fmaxf(acc[j], 0.f);
  }
}

// ---- conv3: [512,64,16,16] -> [512,128,8,8] ----
__global__ __launch_bounds__(256) void conv3_k(const float* __restrict__ in,
                                               const float* __restrict__ W,
                                               const float* __restrict__ bias,
                                               float* __restrict__ out) {
  __shared__ __align__(16) float sIn[16384];   // 64 KB
  int bt = blockIdx.x, tid = threadIdx.x;
  const float4* src = (const float4*)(in + (size_t)bt * 16384);
  for (int i = tid; i < 4096; i += 256) ((float4*)sIn)[i] = src[i];
  __syncthreads();
  int pix = tid & 63, ocs = tid >> 6;   // ocs wave-uniform
  int ho = pix >> 3, wo = pix & 7, hi0 = ho*2-1, wi0 = wo*2-1;
  for (int ocb = 0; ocb < 4; ++ocb) {
    float acc[8];
    int obase = ocs*32 + ocb*8;
    #pragma unroll
    for (int j = 0; j < 8; ++j) acc[j] = bias[obase+j];
    for (int ic = 0; ic < 64; ++ic) {
      float win[9];
      #pragma unroll
      for (int kh = 0; kh < 3; ++kh) {
        int hi = hi0 + kh;
        #pragma unroll
        for (int kw = 0; kw < 3; ++kw) {
          int wi = wi0 + kw;
          win[kh*3+kw] = (hi>=0 && hi<16 && wi>=0 && wi<16) ? sIn[ic*256 + hi*16 + wi] : 0.f;
        }
      }
      #pragma unroll
      for (int j = 0; j < 8; ++j) {
        const float* wp = W + (size_t)(obase+j)*576 + ic*9;
        #pragma unroll
        for (int k = 0; k < 9; ++k) acc[j] += win[k] * wp[k];
      }
    }
    #pragma unroll
    for (int j = 0; j < 8; ++j)
      out[(size_t)(bt*128 + obase + j)*64 + pix] = fmaxf(acc[j], 0.f);
  }
}

// ---- embed: node[bt,n,e] = sum_c c3[bt,c,n] * We[c,e] + be[e] ----
__global__ __launch_bounds__(256) void embed_k(const float* __restrict__ c3,
                                               const float* __restrict__ We,
                                               const float* __restrict__ be,
                                               float* __restrict__ node) {
  __shared__ float sF[64*133];                 // feats[n][c], stride 133 vs bank conflicts
  __shared__ __align__(16) float sWe[8192];
  int bt = blockIdx.x, tid = threadIdx.x;
  const float* src = c3 + (size_t)bt * 8192;
  for (int i = tid; i < 8192; i += 256) sF[(i & 63)*133 + (i >> 6)] = src[i];
  const float4* w4 = (const float4*)We;
  for (int i = tid; i < 2048; i += 256) ((float4*)sWe)[i] = w4[i];
  __syncthreads();
  int lane = tid & 63, w = tid >> 6, nsub = lane >> 4, eb = lane & 15;
  int n0 = w*16 + nsub*4, e0 = eb*4;
  float acc[4][4];
  #pragma unroll
  for (int jj = 0; jj < 4; ++jj)
    #pragma unroll
    for (int ee = 0; ee < 4; ++ee) acc[jj][ee] = be[e0+ee];
  for (int c = 0; c < 128; ++c) {
    float a0 = sF[(n0+0)*133+c];
    float a1 = sF[(n0+1)*133+c];
    float a2 = sF[(n0+2)*133+c];
    float a3 = sF[(n0+3)*133+c];
    const float4 bv = *(const float4*)&sWe[c*64 + e0];
    acc[0][0]+=a0*bv.x; acc[0][1]+=a0*bv.y; acc[0][2]+=a0*bv.z; acc[0][3]+=a0*bv.w;
    acc[1][0]+=a1*bv.x; acc[1][1]+=a1*bv.y; acc[1][2]+=a1*bv.z; acc[1][3]+=a1*bv.w;
    acc[2][0]+=a2*bv.x; acc[2][1]+=a2*bv.y; acc[2][2]+=a2*bv.z; acc[2][3]+=a2*bv.w;
    acc[3][0]+=a3*bv.x; acc[3][1]+=a3*bv.y; acc[3][2]+=a3*bv.z; acc[3][3]+=a3*bv.w;
  }
  float4* nd = (float4*)(node + (size_t)bt * 4096);
  #pragma unroll
  for (int jj = 0; jj < 4; ++jj)
    nd[(n0+jj)*16 + eb] = make_float4(acc[jj][0], acc[jj][1], acc[jj][2], acc[jj][3]);
}

// ---- prep (per b,t): A2 = A@A ; gx = x@Wx0 + A@(x@Wx1) + A2@(x@Wx2) ----
__global__ __launch_bounds__(256) void prep_k(const float* __restrict__ adj,
                                              const float* __restrict__ node,
                                              const float* __restrict__ Wx,
                                              float* __restrict__ A2g,
                                              float* __restrict__ gxg) {
  __shared__ __align__(16) float sA[64*SH], sA2[64*SH], sN[64*SH], sZ[64*SH];
  __shared__ __align__(16) float sWx[12288];
  int bt = blockIdx.x, tid = threadIdx.x;
  {
    const float4* a4 = (const float4*)(adj + (size_t)bt * 4096);
    const float4* n4 = (const float4*)(node + (size_t)bt * 4096);
    for (int i = tid; i < 1024; i += 256) {
      int r = i >> 4, c = (i & 15) * 4;
      *(float4*)&sA[r*SH+c] = a4[i];
      *(float4*)&sN[r*SH+c] = n4[i];
    }
    const float4* w4 = (const float4*)Wx;
    for (int i = tid; i < 3072; i += 256) ((float4*)sWx)[i] = w4[i];
  }
  __syncthreads();
  int lane = tid & 63, w = tid >> 6, nsub = lane >> 4, eb = lane & 15;
  int n0 = w*16 + nsub*4, e0 = eb*4;
  float4* A2out = (float4*)(A2g + (size_t)bt * 4096);
  float4* gxout = (float4*)(gxg + (size_t)bt * 4096);
  {
    float t[4][4] = {};
    mm16(sA, sA, SH, t, n0, e0);
    #pragma unroll
    for (int jj = 0; jj < 4; ++jj) {
      float4 v = make_float4(t[jj][0], t[jj][1], t[jj][2], t[jj][3]);
      *(float4*)&sA2[(n0+jj)*SH+e0] = v;
      A2out[(n0+jj)*16 + eb] = v;
    }
  }
  {
    float t[4][4] = {};
    mm16(sN, sWx + 4096, 64, t, n0, e0);       // z1 = x @ Wx1
    #pragma unroll
    for (int jj = 0; jj < 4; ++jj)
      *(float4*)&sZ[(n0+jj)*SH+e0] = make_float4(t[jj][0], t[jj][1], t[jj][2], t[jj][3]);
  }
  __syncthreads();                             // sZ (z1) and sA2 complete
  float gx[4][4] = {};
  mm16(sA, sZ, SH, gx, n0, e0);                // gx = A @ z1
  __syncthreads();                             // everyone done reading z1
  {
    float t[4][4] = {};
    mm16(sN, sWx + 8192, 64, t, n0, e0);       // z2 = x @ Wx2
    #pragma unroll
    for (int jj = 0; jj < 4; ++jj)
      *(float4*)&sZ[(n0+jj)*SH+e0] = make_float4(t[jj][0], t[jj][1], t[jj][2], t[jj][3]);
  }
  __syncthreads();                             // sZ (z2) ready
  mm16(sA2, sZ, SH, gx, n0, e0);               // gx += A2 @ z2
  mm16(sN, sWx, 64, gx, n0, e0);               // gx += x @ Wx0
  #pragma unroll
  for (int jj = 0; jj < 4; ++jj)
    gxout[(n0+jj)*16 + eb] = make_float4(gx[jj][0], gx[jj][1], gx[jj][2], gx[jj][3]);
}

// ---- sequential recurrence: one block per batch chain, T=64 internal steps ----
__global__ __launch_bounds__(512) void seq_k(
    const float* __restrict__ adj, const float* __restrict__ A2g,
    const float* __restrict__ gxg, const float* __restrict__ h0,
    const float* __restrict__ Wh, const float* __restrict__ bg,
    const float* __restrict__ tau, const float* __restrict__ Apv,
    const float* __restrict__ Wd1, const float* __restrict__ bd1,
    const float* __restrict__ Wd2, const float* __restrict__ bd2,
    const float* __restrict__ Wd3, const float* __restrict__ bd3,
    float* __restrict__ out) {
  __shared__ __align__(16) float sH[64*SH];
  __shared__ __align__(16) float sWh[12288];
  __shared__ __align__(16) float sZ[2*64*SH];
  __shared__ __align__(16) float sA[64*SH];
  __shared__ __align__(16) float sA2[64*SH];
  __shared__ __align__(16) float sPart[2048];
  __shared__ float sm[64], sd1[128], sd2[64];
  __shared__ float sbg[64], sit[64], sAp[64];
  int b = blockIdx.x, tid = threadIdx.x;
  int lane = tid & 63, w = tid >> 6, nsub = lane >> 4, eb = lane & 15;
  int n0 = w*8 + nsub*2, e0 = eb*4;      // wave-private row range [w*8, w*8+8)
  {
    const float4* h4 = (const float4*)(h0 + (size_t)b * 4096);
    for (int i = tid; i < 1024; i += 512) {
      int r = i >> 4, c = (i & 15) * 4;
      *(float4*)&sH[r*SH+c] = h4[i];
    }
    const float4* w4 = (const float4*)Wh;
    for (int i = tid; i < 3072; i += 512) ((float4*)sWh)[i] = w4[i];
    if (tid < 64) { sbg[tid] = bg[tid]; sit[tid] = 1.0f / tau[tid]; sAp[tid] = Apv[tid]; }
  }
  __syncthreads();
  for (int t = 0; t < 64; ++t) {
    size_t bt = (size_t)(b*64 + t);
    // stage A, A2 for this step
    const float4* a4 = (const float4*)(adj + bt * 4096);
    const float4* q4 = (const float4*)(A2g + bt * 4096);
    for (int i = tid; i < 1024; i += 512) {
      int r = i >> 4, c = (i & 15) * 4;
      *(float4*)&sA[r*SH+c] = a4[i];
      *(float4*)&sA2[r*SH+c] = q4[i];
    }
    __syncthreads();
    // phase1: zh1 = h@Wh1, zh2 = h@Wh2 -> sZ
    {
      float z1[2][4] = {}, z2[2][4] = {};
      mm8(sH, sWh + 4096, 64, z1, n0, e0);
      mm8(sH, sWh + 8192, 64, z2, n0, e0);
      #pragma unroll
      for (int jj = 0; jj < 2; ++jj) {
        *(float4*)&sZ[(n0+jj)*SH+e0]        = make_float4(z1[jj][0], z1[jj][1], z1[jj][2], z1[jj][3]);
        *(float4*)&sZ[4352 + (n0+jj)*SH+e0] = make_float4(z2[jj][0], z2[jj][1], z2[jj][2], z2[jj][3]);
      }
    }
    __syncthreads();
    // phase2: gc = h@Wh0 + A@zh1 + A2@zh2 + gx + bg ; h update; mean partials
    {
      float acc[2][4];
      const float4* g4 = (const float4*)(gxg + bt * 4096);
      #pragma unroll
      for (int jj = 0; jj < 2; ++jj) {
        float4 gv = g4[(n0+jj)*16 + eb];
        acc[jj][0] = gv.x + sbg[e0+0];
        acc[jj][1] = gv.y + sbg[e0+1];
        acc[jj][2] = gv.z + sbg[e0+2];
        acc[jj][3] = gv.w + sbg[e0+3];
      }
      mm8(sH, sWh, 64, acc, n0, e0);
      mm8(sA,  sZ,        SH, acc, n0, e0);
      mm8(sA2, sZ + 4352, SH, acc, n0, e0);
      float psum[4] = {0.f, 0.f, 0.f, 0.f};
      #pragma unroll
      for (int jj = 0; jj < 2; ++jj) {
        float4 hv = *(const float4*)&sH[(n0+jj)*SH+e0];
        float hc[4] = {hv.x, hv.y, hv.z, hv.w};
        float hn[4];
        #pragma unroll
        for (int ee = 0; ee < 4; ++ee) {
          float f = tanhf(acc[jj][ee]);
          hn[ee] = hc[ee] + DT_C * (-(sit[e0+ee] + f) * hc[ee] + f * sAp[e0+ee]);
          psum[ee] += hn[ee];
        }
        *(float4*)&sH[(n0+jj)*SH+e0] = make_float4(hn[0], hn[1], hn[2], hn[3]);
      }
      int g = w*4 + nsub;
      *(float4*)&sPart[g*64 + e0] = make_float4(psum[0], psum[1], psum[2], psum[3]);
    }
    __syncthreads();
    if (tid < 64) {
      float s = 0.f;
      #pragma unroll
      for (int g = 0; g < 32; ++g) s += sPart[g*64 + tid];
      sm[tid] = s * (1.0f / 64.0f);
    }
    __syncthreads();
    if (tid < 128) {
      float a = bd1[tid];
      for (int e = 0; e < 64; ++e) a += sm[e] * Wd1[e*128 + tid];
      sd1[tid] = fmaxf(a, 0.f);
    }
    __syncthreads();
    if (tid < 64) {
      float a = bd2[tid];
      for (int i = 0; i < 128; ++i) a += sd1[i] * Wd2[i*64 + tid];
      sd2[tid] = fmaxf(a, 0.f);
    }
    __syncthreads();
    if (tid == 0) {
      float a = bd3[0];
      for (int j = 0; j < 64; ++j) a += sd2[j] * Wd3[j];
      out[b*64 + t] = a;
    }
    __syncthreads();
  }
  // final_h
  for (int i = tid; i < 4096; i += 512)
    out[512 + (size_t)b * 4096 + i] = sH[(i >> 6)*SH + (i & 63)];
}

extern "C" void kernel_launch(void* const* d_in, const int* in_sizes, int n_in,
                              void* d_out, int out_size, void* d_ws, size_t ws_size,
                              hipStream_t stream) {
  const float* frames = (const float*)d_in[0];
  const float* adj    = (const float*)d_in[1];
  const float* h0     = (const float*)d_in[2];
  const float* Wc1 = (const float*)d_in[3];  const float* bc1 = (const float*)d_in[4];
  const float* Wc2 = (const float*)d_in[5];  const float* bc2 = (const float*)d_in[6];
  const float* Wc3 = (const float*)d_in[7];  const float* bc3 = (const float*)d_in[8];
  const float* We  = (const float*)d_in[9];  const float* be  = (const float*)d_in[10];
  const float* Wh  = (const float*)d_in[11]; const float* Wx  = (const float*)d_in[12];
  const float* bg  = (const float*)d_in[13]; const float* tau = (const float*)d_in[14];
  const float* Ap  = (const float*)d_in[15];
  const float* Wd1 = (const float*)d_in[16]; const float* bd1 = (const float*)d_in[17];
  const float* Wd2 = (const float*)d_in[18]; const float* bd2 = (const float*)d_in[19];
  const float* Wd3 = (const float*)d_in[20]; const float* bd3 = (const float*)d_in[21];

  float* ws = (float*)d_ws;
  // workspace layout (floats), with reuse; total = 25,165,824 floats (100.7 MB)
  float* c1   = ws;              // [0 .. 16,777,216)           conv1 out
  float* c2   = ws + 16777216;   // [16,777,216 .. 25,165,824)  conv2 out
  float* c3   = ws;              // reuse c1 region: 4,194,304  conv3 out (c1 dead)
  float* node = ws + 4194304;    // 2,097,152
  float* A2   = ws + 6291456;    // 2,097,152
  float* gx   = ws + 8388608;    // 2,097,152
  float* out  = (float*)d_out;

  conv1_k<<<512, 256, 0, stream>>>(frames, Wc1, bc1, c1);
  conv2_k<<<512, 256, 0, stream>>>(c1, Wc2, bc2, c2);
  conv3_k<<<512, 256, 0, stream>>>(c2, Wc3, bc3, c3);
  embed_k<<<512, 256, 0, stream>>>(c3, We, be, node);
  prep_k <<<512, 256, 0, stream>>>(adj, node, Wx, A2, gx);
  seq_k  <<<8,   512, 0, stream>>>(adj, A2, gx, h0, Wh, bg, tau, Ap,
                                   Wd1, bd1, Wd2, bd2, Wd3, bd3, out);
}

// Round 2
// 875.357 us; speedup vs baseline: 2.1114x; 2.1114x over previous
//
#include <hip/hip_runtime.h>

#define SH 68            // padded LDS row stride (floats) for fp32 prep kernels
#define DT_C 0.1f

typedef short bfrag __attribute__((ext_vector_type(8)));   // 8 bf16 (4 VGPR)
typedef float f32x4 __attribute__((ext_vector_type(4)));

union FU { bfrag v; unsigned short s[8]; uint4 q; };

__device__ __forceinline__ unsigned short bf16_rn(float x) {
  union { float f; unsigned u; } v; v.f = x;
  unsigned r = v.u + 0x7fffu + ((v.u >> 16) & 1u);
  return (unsigned short)(r >> 16);
}
__device__ __forceinline__ float bf16_tof(unsigned short h) {
  union { unsigned u; float f; } v; v.u = ((unsigned)h) << 16; return v.f;
}
__device__ __forceinline__ float tanh_f(float x) {
  // tanh(x) = 1 - 2/(exp(2x)+1); saturates correctly at +/-inf
  return 1.0f - 2.0f / (__expf(2.0f * x) + 1.0f);
}
__device__ __forceinline__ void unpk(uint4 q0, uint4 q1, FU& h, FU& l) {
  unsigned u[8] = {q0.x, q0.y, q0.z, q0.w, q1.x, q1.y, q1.z, q1.w};
  #pragma unroll
  for (int i = 0; i < 8; ++i) {
    h.s[i] = (unsigned short)(u[i] & 0xffffu);
    l.s[i] = (unsigned short)(u[i] >> 16);
  }
}

// ---- fp32 4x4-block 64-K matmul helper (A stride SH; acc += A[n0..][*] * B[*][e0..]) ----
__device__ __forceinline__ void mm16(const float* __restrict__ A,
                                     const float* __restrict__ B, int sb,
                                     float acc[4][4], int n0, int e0) {
  #pragma unroll 2
  for (int k = 0; k < 64; ++k) {
    float a0 = A[(n0+0)*SH+k];
    float a1 = A[(n0+1)*SH+k];
    float a2 = A[(n0+2)*SH+k];
    float a3 = A[(n0+3)*SH+k];
    const float4 bv = *(const float4*)(B + k*sb + e0);
    acc[0][0]+=a0*bv.x; acc[0][1]+=a0*bv.y; acc[0][2]+=a0*bv.z; acc[0][3]+=a0*bv.w;
    acc[1][0]+=a1*bv.x; acc[1][1]+=a1*bv.y; acc[1][2]+=a1*bv.z; acc[1][3]+=a1*bv.w;
    acc[2][0]+=a2*bv.x; acc[2][1]+=a2*bv.y; acc[2][2]+=a2*bv.z; acc[2][3]+=a2*bv.w;
    acc[3][0]+=a3*bv.x; acc[3][1]+=a3*bv.y; acc[3][2]+=a3*bv.z; acc[3][3]+=a3*bv.w;
  }
}

// ---- conv1: [512,3,64,64] -> [512,32,32,32], k3 s2 p1, relu ----
__global__ __launch_bounds__(256) void conv1_k(const float* __restrict__ frames,
                                               const float* __restrict__ W,
                                               const float* __restrict__ bias,
                                               float* __restrict__ out) {
  __shared__ __align__(16) float sIn[12288];
  int bt = blockIdx.x, tid = threadIdx.x;
  const float4* src = (const float4*)(frames + (size_t)bt * 12288);
  for (int i = tid; i < 3072; i += 256) ((float4*)sIn)[i] = src[i];
  __syncthreads();
  for (int p = tid; p < 1024; p += 256) {
    int ho = p >> 5, wo = p & 31, hi0 = ho*2-1, wi0 = wo*2-1;
    for (int ocb = 0; ocb < 4; ++ocb) {
      float acc[8];
      #pragma unroll
      for (int j = 0; j < 8; ++j) acc[j] = bias[ocb*8+j];
      for (int ic = 0; ic < 3; ++ic) {
        float win[9];
        #pragma unroll
        for (int kh = 0; kh < 3; ++kh) {
          int hi = hi0 + kh;
          #pragma unroll
          for (int kw = 0; kw < 3; ++kw) {
            int wi = wi0 + kw;
            win[kh*3+kw] = (hi>=0 && hi<64 && wi>=0 && wi<64) ? sIn[ic*4096 + hi*64 + wi] : 0.f;
          }
        }
        #pragma unroll
        for (int j = 0; j < 8; ++j) {
          const float* wp = W + (size_t)(ocb*8+j)*27 + ic*9;
          #pragma unroll
          for (int k = 0; k < 9; ++k) acc[j] += win[k] * wp[k];
        }
      }
      #pragma unroll
      for (int j = 0; j < 8; ++j)
        out[(size_t)(bt*32 + ocb*8 + j)*1024 + p] = fmaxf(acc[j], 0.f);
    }
  }
}

// ---- conv2: [512,32,32,32] -> [512,64,16,16] ----
__global__ __launch_bounds__(256) void conv2_k(const float* __restrict__ in,
                                               const float* __restrict__ W,
                                               const float* __restrict__ bias,
                                               float* __restrict__ out) {
  __shared__ __align__(16) float sIn[32768];
  int bt = blockIdx.x, tid = threadIdx.x;
  const float4* src = (const float4*)(in + (size_t)bt * 32768);
  for (int i = tid; i < 8192; i += 256) ((float4*)sIn)[i] = src[i];
  __syncthreads();
  int ho = tid >> 4, wo = tid & 15, hi0 = ho*2-1, wi0 = wo*2-1;
  for (int ocb = 0; ocb < 8; ++ocb) {
    float acc[8];
    #pragma unroll
    for (int j = 0; j < 8; ++j) acc[j] = bias[ocb*8+j];
    for (int ic = 0; ic < 32; ++ic) {
      float win[9];
      #pragma unroll
      for (int kh = 0; kh < 3; ++kh) {
        int hi = hi0 + kh;
        #pragma unroll
        for (int kw = 0; kw < 3; ++kw) {
          int wi = wi0 + kw;
          win[kh*3+kw] = (hi>=0 && hi<32 && wi>=0 && wi<32) ? sIn[ic*1024 + hi*32 + wi] : 0.f;
        }
      }
      #pragma unroll
      for (int j = 0; j < 8; ++j) {
        const float* wp = W + (size_t)(ocb*8+j)*288 + ic*9;
        #pragma unroll
        for (int k = 0; k < 9; ++k) acc[j] += win[k] * wp[k];
      }
    }
    #pragma unroll
    for (int j = 0; j < 8; ++j)
      out[(size_t)(bt*64 + ocb*8 + j)*256 + tid] = fmaxf(acc[j], 0.f);
  }
}

// ---- conv3: [512,64,16,16] -> [512,128,8,8] ----
__global__ __launch_bounds__(256) void conv3_k(const float* __restrict__ in,
                                               const float* __restrict__ W,
                                               const float* __restrict__ bias,
                                               float* __restrict__ out) {
  __shared__ __align__(16) float sIn[16384];
  int bt = blockIdx.x, tid = threadIdx.x;
  const float4* src = (const float4*)(in + (size_t)bt * 16384);
  for (int i = tid; i < 4096; i += 256) ((float4*)sIn)[i] = src[i];
  __syncthreads();
  int pix = tid & 63, ocs = tid >> 6;
  int ho = pix >> 3, wo = pix & 7, hi0 = ho*2-1, wi0 = wo*2-1;
  for (int ocb = 0; ocb < 4; ++ocb) {
    float acc[8];
    int obase = ocs*32 + ocb*8;
    #pragma unroll
    for (int j = 0; j < 8; ++j) acc[j] = bias[obase+j];
    for (int ic = 0; ic < 64; ++ic) {
      float win[9];
      #pragma unroll
      for (int kh = 0; kh < 3; ++kh) {
        int hi = hi0 + kh;
        #pragma unroll
        for (int kw = 0; kw < 3; ++kw) {
          int wi = wi0 + kw;
          win[kh*3+kw] = (hi>=0 && hi<16 && wi>=0 && wi<16) ? sIn[ic*256 + hi*16 + wi] : 0.f;
        }
      }
      #pragma unroll
      for (int j = 0; j < 8; ++j) {
        const float* wp = W + (size_t)(obase+j)*576 + ic*9;
        #pragma unroll
        for (int k = 0; k < 9; ++k) acc[j] += win[k] * wp[k];
      }
    }
    #pragma unroll
    for (int j = 0; j < 8; ++j)
      out[(size_t)(bt*128 + obase + j)*64 + pix] = fmaxf(acc[j], 0.f);
  }
}

// ---- embed: node[bt,n,e] = sum_c c3[bt,c,n] * We[c,e] + be[e] ----
__global__ __launch_bounds__(256) void embed_k(const float* __restrict__ c3,
                                               const float* __restrict__ We,
                                               const float* __restrict__ be,
                                               float* __restrict__ node) {
  __shared__ float sF[64*133];
  __shared__ __align__(16) float sWe[8192];
  int bt = blockIdx.x, tid = threadIdx.x;
  const float* src = c3 + (size_t)bt * 8192;
  for (int i = tid; i < 8192; i += 256) sF[(i & 63)*133 + (i >> 6)] = src[i];
  const float4* w4 = (const float4*)We;
  for (int i = tid; i < 2048; i += 256) ((float4*)sWe)[i] = w4[i];
  __syncthreads();
  int lane = tid & 63, w = tid >> 6, nsub = lane >> 4, eb = lane & 15;
  int n0 = w*16 + nsub*4, e0 = eb*4;
  float acc[4][4];
  #pragma unroll
  for (int jj = 0; jj < 4; ++jj)
    #pragma unroll
    for (int ee = 0; ee < 4; ++ee) acc[jj][ee] = be[e0+ee];
  for (int c = 0; c < 128; ++c) {
    float a0 = sF[(n0+0)*133+c];
    float a1 = sF[(n0+1)*133+c];
    float a2 = sF[(n0+2)*133+c];
    float a3 = sF[(n0+3)*133+c];
    const float4 bv = *(const float4*)&sWe[c*64 + e0];
    acc[0][0]+=a0*bv.x; acc[0][1]+=a0*bv.y; acc[0][2]+=a0*bv.z; acc[0][3]+=a0*bv.w;
    acc[1][0]+=a1*bv.x; acc[1][1]+=a1*bv.y; acc[1][2]+=a1*bv.z; acc[1][3]+=a1*bv.w;
    acc[2][0]+=a2*bv.x; acc[2][1]+=a2*bv.y; acc[2][2]+=a2*bv.z; acc[2][3]+=a2*bv.w;
    acc[3][0]+=a3*bv.x; acc[3][1]+=a3*bv.y; acc[3][2]+=a3*bv.z; acc[3][3]+=a3*bv.w;
  }
  float4* nd = (float4*)(node + (size_t)bt * 4096);
  #pragma unroll
  for (int jj = 0; jj < 4; ++jj)
    nd[(n0+jj)*16 + eb] = make_float4(acc[jj][0], acc[jj][1], acc[jj][2], acc[jj][3]);
}

// ---- prep: A2=A@A ; gx = x@Wx0 + A@(x@Wx1) + A2@(x@Wx2); emit bf16 A, A2 + fp32 gx ----
__global__ __launch_bounds__(256) void prep_k(const float* __restrict__ adj,
                                              const float* __restrict__ node,
                                              const float* __restrict__ Wx,
                                              unsigned short* __restrict__ Abf,
                                              unsigned short* __restrict__ A2bf,
                                              float* __restrict__ gxg) {
  __shared__ __align__(16) float sA[64*SH], sA2[64*SH], sN[64*SH], sZ[64*SH];
  __shared__ __align__(16) float sWx[12288];
  int bt = blockIdx.x, tid = threadIdx.x;
  {
    const float4* a4 = (const float4*)(adj + (size_t)bt * 4096);
    const float4* n4 = (const float4*)(node + (size_t)bt * 4096);
    for (int i = tid; i < 1024; i += 256) {
      int r = i >> 4, c = (i & 15) * 4;
      *(float4*)&sA[r*SH+c] = a4[i];
      *(float4*)&sN[r*SH+c] = n4[i];
    }
    const float4* w4 = (const float4*)Wx;
    for (int i = tid; i < 3072; i += 256) ((float4*)sWx)[i] = w4[i];
  }
  __syncthreads();
  int lane = tid & 63, w = tid >> 6, nsub = lane >> 4, eb = lane & 15;
  int n0 = w*16 + nsub*4, e0 = eb*4;
  float4* gxout = (float4*)(gxg + (size_t)bt * 4096);
  // Abf (bf16 of adjacency, row-major)
  for (int i = tid; i < 1024; i += 256) {
    int r = i >> 4, c0 = (i & 15) * 4;
    ushort4 o;
    o.x = bf16_rn(sA[r*SH+c0+0]); o.y = bf16_rn(sA[r*SH+c0+1]);
    o.z = bf16_rn(sA[r*SH+c0+2]); o.w = bf16_rn(sA[r*SH+c0+3]);
    *(ushort4*)&Abf[(size_t)bt*4096 + r*64 + c0] = o;
  }
  {
    float a2t[4][4] = {};
    mm16(sA, sA, SH, a2t, n0, e0);
    #pragma unroll
    for (int jj = 0; jj < 4; ++jj) {
      *(float4*)&sA2[(n0+jj)*SH+e0] = make_float4(a2t[jj][0], a2t[jj][1], a2t[jj][2], a2t[jj][3]);
      ushort4 o;
      o.x = bf16_rn(a2t[jj][0]); o.y = bf16_rn(a2t[jj][1]);
      o.z = bf16_rn(a2t[jj][2]); o.w = bf16_rn(a2t[jj][3]);
      *(ushort4*)&A2bf[(size_t)bt*4096 + (n0+jj)*64 + e0] = o;
    }
  }
  {
    float t[4][4] = {};
    mm16(sN, sWx + 4096, 64, t, n0, e0);       // z1 = x @ Wx1
    #pragma unroll
    for (int jj = 0; jj < 4; ++jj)
      *(float4*)&sZ[(n0+jj)*SH+e0] = make_float4(t[jj][0], t[jj][1], t[jj][2], t[jj][3]);
  }
  __syncthreads();
  float gx[4][4] = {};
  mm16(sA, sZ, SH, gx, n0, e0);                // gx = A @ z1
  __syncthreads();
  {
    float t[4][4] = {};
    mm16(sN, sWx + 8192, 64, t, n0, e0);       // z2 = x @ Wx2
    #pragma unroll
    for (int jj = 0; jj < 4; ++jj)
      *(float4*)&sZ[(n0+jj)*SH+e0] = make_float4(t[jj][0], t[jj][1], t[jj][2], t[jj][3]);
  }
  __syncthreads();
  mm16(sA2, sZ, SH, gx, n0, e0);               // gx += A2 @ z2
  mm16(sN, sWx, 64, gx, n0, e0);               // gx += x @ Wx0
  #pragma unroll
  for (int jj = 0; jj < 4; ++jj)
    gxout[(n0+jj)*16 + eb] = make_float4(gx[jj][0], gx[jj][1], gx[jj][2], gx[jj][3]);
}

// ---- Wh split: WhT_hi/lo[k3][dout][din] bf16 ----
__global__ void wsplit_k(const float* __restrict__ Wh,
                         unsigned short* __restrict__ WTh,
                         unsigned short* __restrict__ WTl) {
  int i = blockIdx.x * 256 + threadIdx.x;
  if (i < 3*4096) {
    int k3 = i >> 12, rem = i & 4095, din = rem >> 6, dout = rem & 63;
    float v = Wh[i];
    unsigned short hi = bf16_rn(v);
    WTh[k3*4096 + dout*64 + din] = hi;
    WTl[k3*4096 + dout*64 + din] = bf16_rn(v - bf16_tof(hi));
  }
}

#define MFMA(a, bb, cc) __builtin_amdgcn_mfma_f32_16x16x32_bf16((a), (bb), (cc), 0, 0, 0)

// ---- sequential recurrence via MFMA: one block per batch chain ----
__global__ __launch_bounds__(512, 2) void seq2_k(
    const unsigned short* __restrict__ Abf, const unsigned short* __restrict__ A2bf,
    const float* __restrict__ gxg, const float* __restrict__ h0,
    const unsigned short* __restrict__ WTh, const unsigned short* __restrict__ WTl,
    const float* __restrict__ bg, const float* __restrict__ tau, const float* __restrict__ Apv,
    float* __restrict__ mout, float* __restrict__ out) {
  __shared__ unsigned short sHh[64*72], sHl[64*72];       // h hi/lo, A-operand layout
  __shared__ unsigned short sA[2][64*72], sA2[2][64*72];  // staged A/A2 (bf16 hi), dbuf
  __shared__ unsigned szT[2][64*68];                      // z1,z2 transposed, packed hi|lo<<16
  __shared__ float sPart[64*17];
  int b = blockIdx.x, tid = threadIdx.x;
  int lane = tid & 63, w = tid >> 6, g = lane >> 4, c = lane & 15;
  int mt = w & 3, nt0 = (w >> 2) * 2;
  int e0_ = nt0*16 + c, e1_ = e0_ + 16;
  int mrow = mt*16 + 4*g;                 // D-frag base row
  float itau[2] = {1.f/tau[e0_], 1.f/tau[e1_]};
  float apv_[2] = {Apv[e0_], Apv[e1_]};
  float bgv_[2] = {bg[e0_], bg[e1_]};
  // hoist all weight fragments into registers for the whole t-loop
  FU wf[3][2][2][2];                      // [k3][tt][kt][hi/lo]
  #pragma unroll
  for (int k3 = 0; k3 < 3; ++k3)
    #pragma unroll
    for (int tt = 0; tt < 2; ++tt)
      #pragma unroll
      for (int kt = 0; kt < 2; ++kt) {
        int off = k3*4096 + ((nt0+tt)*16 + c)*64 + kt*32 + 8*g;
        wf[k3][tt][kt][0].q = *(const uint4*)(WTh + off);
        wf[k3][tt][kt][1].q = *(const uint4*)(WTl + off);
      }
  // h master copy in registers (D-frag ownership)
  float hm[2][4];
  #pragma unroll
  for (int tt = 0; tt < 2; ++tt)
    #pragma unroll
    for (int r = 0; r < 4; ++r)
      hm[tt][r] = h0[(size_t)b*4096 + (mrow+r)*64 + (tt ? e1_ : e0_)];
  #pragma unroll
  for (int tt = 0; tt < 2; ++tt) {
    int e = tt ? e1_ : e0_;
    #pragma unroll
    for (int r = 0; r < 4; ++r) {
      unsigned short hi = bf16_rn(hm[tt][r]);
      sHh[(mrow+r)*72 + e] = hi;
      sHl[(mrow+r)*72 + e] = bf16_rn(hm[tt][r] - bf16_tof(hi));
    }
  }
  {  // stage t=0 A/A2
    uint4 pa  = *(const uint4*)(Abf  + (size_t)b*64*4096 + tid*8);
    uint4 pa2 = *(const uint4*)(A2bf + (size_t)b*64*4096 + tid*8);
    int row = tid >> 3, k0 = (tid & 7) * 8;
    *(uint4*)&sA[0][row*72 + k0]  = pa;
    *(uint4*)&sA2[0][row*72 + k0] = pa2;
  }
  __syncthreads();
  #pragma unroll 1
  for (int t = 0; t < 64; ++t) {
    int cur = t & 1;
    size_t bt = (size_t)b*64 + t;
    // prefetch next step's A/A2 (global -> regs; LDS-write after B1)
    int tn = (t < 63) ? t + 1 : t;
    uint4 pa  = *(const uint4*)(Abf  + ((size_t)b*64 + tn)*4096 + tid*8);
    uint4 pa2 = *(const uint4*)(A2bf + ((size_t)b*64 + tn)*4096 + tid*8);
    // gx loads issued early; consumed after MFMAs
    float gxv[2][4];
    {
      const float* gp = gxg + bt*4096;
      #pragma unroll
      for (int tt = 0; tt < 2; ++tt)
        #pragma unroll
        for (int r = 0; r < 4; ++r)
          gxv[tt][r] = gp[(mrow+r)*64 + (tt ? e1_ : e0_)];
    }
    // ---- z-phase: z1 = h@Wh1, z2 = h@Wh2 ----
    FU ha[2][2];                          // h A-frags [kt][hi/lo], reused in gc-phase
    #pragma unroll
    for (int kt = 0; kt < 2; ++kt) {
      int ao = (mt*16 + c)*72 + kt*32 + 8*g;
      ha[kt][0].q = *(const uint4*)&sHh[ao];
      ha[kt][1].q = *(const uint4*)&sHl[ao];
    }
    #pragma unroll
    for (int tt = 0; tt < 2; ++tt) {
      f32x4 a1 = {0.f, 0.f, 0.f, 0.f}, a2 = {0.f, 0.f, 0.f, 0.f};
      #pragma unroll
      for (int kt = 0; kt < 2; ++kt) {
        a1 = MFMA(ha[kt][0].v, wf[1][tt][kt][0].v, a1);
        a1 = MFMA(ha[kt][1].v, wf[1][tt][kt][0].v, a1);
        a1 = MFMA(ha[kt][0].v, wf[1][tt][kt][1].v, a1);
        a2 = MFMA(ha[kt][0].v, wf[2][tt][kt][0].v, a2);
        a2 = MFMA(ha[kt][1].v, wf[2][tt][kt][0].v, a2);
        a2 = MFMA(ha[kt][0].v, wf[2][tt][kt][1].v, a2);
      }
      int e = tt ? e1_ : e0_;
      unsigned pk1[4], pk2[4];
      #pragma unroll
      for (int r = 0; r < 4; ++r) {
        unsigned short h1 = bf16_rn(a1[r]);
        pk1[r] = (unsigned)h1 | ((unsigned)bf16_rn(a1[r] - bf16_tof(h1)) << 16);
        unsigned short h2 = bf16_rn(a2[r]);
        pk2[r] = (unsigned)h2 | ((unsigned)bf16_rn(a2[r] - bf16_tof(h2)) << 16);
      }
      *(uint4*)&szT[0][e*68 + mt*16 + 4*g] = make_uint4(pk1[0], pk1[1], pk1[2], pk1[3]);
      *(uint4*)&szT[1][e*68 + mt*16 + 4*g] = make_uint4(pk2[0], pk2[1], pk2[2], pk2[3]);
    }
    __syncthreads();   // B1: szT ready; sHh/sHl reads done
    // ---- gc-phase: gc = h@Wh0 + A@z1 + A2@z2 + gx + bg ----
    f32x4 acc[2] = {{0.f,0.f,0.f,0.f}, {0.f,0.f,0.f,0.f}};
    #pragma unroll
    for (int kt = 0; kt < 2; ++kt) {
      FU aA, aA2;
      int ao = (mt*16 + c)*72 + kt*32 + 8*g;
      aA.q  = *(const uint4*)&sA[cur][ao];
      aA2.q = *(const uint4*)&sA2[cur][ao];
      #pragma unroll
      for (int tt = 0; tt < 2; ++tt) {
        int e = tt ? e1_ : e0_;
        acc[tt] = MFMA(ha[kt][0].v, wf[0][tt][kt][0].v, acc[tt]);
        acc[tt] = MFMA(ha[kt][1].v, wf[0][tt][kt][0].v, acc[tt]);
        acc[tt] = MFMA(ha[kt][0].v, wf[0][tt][kt][1].v, acc[tt]);
        uint4 q0 = *(const uint4*)&szT[0][e*68 + kt*32 + 8*g];
        uint4 q1 = *(const uint4*)&szT[0][e*68 + kt*32 + 8*g + 4];
        FU zh, zl; unpk(q0, q1, zh, zl);
        acc[tt] = MFMA(aA.v, zh.v, acc[tt]);
        acc[tt] = MFMA(aA.v, zl.v, acc[tt]);
        q0 = *(const uint4*)&szT[1][e*68 + kt*32 + 8*g];
        q1 = *(const uint4*)&szT[1][e*68 + kt*32 + 8*g + 4];
        unpk(q0, q1, zh, zl);
        acc[tt] = MFMA(aA2.v, zh.v, acc[tt]);
        acc[tt] = MFMA(aA2.v, zl.v, acc[tt]);
      }
    }
    // h update + write-back + mean partials
    #pragma unroll
    for (int tt = 0; tt < 2; ++tt) {
      int e = tt ? e1_ : e0_;
      float ps = 0.f;
      #pragma unroll
      for (int r = 0; r < 4; ++r) {
        float gc = acc[tt][r] + gxv[tt][r] + bgv_[tt];
        float f = tanh_f(gc);
        float h_ = hm[tt][r];
        float hn = h_ + DT_C * (-(itau[tt] + f) * h_ + f * apv_[tt]);
        hm[tt][r] = hn;
        ps += hn;
        unsigned short hi = bf16_rn(hn);
        sHh[(mrow+r)*72 + e] = hi;
        sHl[(mrow+r)*72 + e] = bf16_rn(hn - bf16_tof(hi));
      }
      sPart[e*17 + mt*4 + g] = ps;
    }
    {  // staging write for next step
      int row = tid >> 3, k0 = (tid & 7) * 8;
      *(uint4*)&sA[cur^1][row*72 + k0]  = pa;
      *(uint4*)&sA2[cur^1][row*72 + k0] = pa2;
    }
    __syncthreads();   // B3: h/staging/sPart visible
    if (tid < 64) {
      float s = 0.f;
      #pragma unroll
      for (int j = 0; j < 16; ++j) s += sPart[tid*17 + j];
      mout[bt*64 + tid] = s * (1.0f / 64.0f);
    }
  }
  // final_h (fp32 master copy)
  #pragma unroll
  for (int tt = 0; tt < 2; ++tt)
    #pragma unroll
    for (int r = 0; r < 4; ++r)
      out[512 + (size_t)b*4096 + (mrow+r)*64 + (tt ? e1_ : e0_)] = hm[tt][r];
}

// ---- decoder MLP for all (b,t) in parallel ----
__global__ __launch_bounds__(128) void dec_k(const float* __restrict__ mout,
                                             const float* __restrict__ Wd1, const float* __restrict__ bd1,
                                             const float* __restrict__ Wd2, const float* __restrict__ bd2,
                                             const float* __restrict__ Wd3, const float* __restrict__ bd3,
                                             float* __restrict__ out) {
  __shared__ float sm[64], sd1[128], sd2[64];
  int bt = blockIdx.x, tid = threadIdx.x;
  if (tid < 64) sm[tid] = mout[(size_t)bt*64 + tid];
  __syncthreads();
  {
    float a = bd1[tid];
    #pragma unroll 8
    for (int e = 0; e < 64; ++e) a += sm[e] * Wd1[e*128 + tid];
    sd1[tid] = fmaxf(a, 0.f);
  }
  __syncthreads();
  if (tid < 64) {
    float a = bd2[tid];
    #pragma unroll 8
    for (int i = 0; i < 128; ++i) a += sd1[i] * Wd2[i*64 + tid];
    sd2[tid] = fmaxf(a, 0.f);
  }
  __syncthreads();
  if (tid < 64) {
    float p = sd2[tid] * Wd3[tid];
    #pragma unroll
    for (int off = 32; off > 0; off >>= 1) p += __shfl_down(p, off, 64);
    if (tid == 0) out[bt] = p + bd3[0];
  }
}

extern "C" void kernel_launch(void* const* d_in, const int* in_sizes, int n_in,
                              void* d_out, int out_size, void* d_ws, size_t ws_size,
                              hipStream_t stream) {
  const float* frames = (const float*)d_in[0];
  const float* adj    = (const float*)d_in[1];
  const float* h0     = (const float*)d_in[2];
  const float* Wc1 = (const float*)d_in[3];  const float* bc1 = (const float*)d_in[4];
  const float* Wc2 = (const float*)d_in[5];  const float* bc2 = (const float*)d_in[6];
  const float* Wc3 = (const float*)d_in[7];  const float* bc3 = (const float*)d_in[8];
  const float* We  = (const float*)d_in[9];  const float* be  = (const float*)d_in[10];
  const float* Wh  = (const float*)d_in[11]; const float* Wx  = (const float*)d_in[12];
  const float* bg  = (const float*)d_in[13]; const float* tau = (const float*)d_in[14];
  const float* Ap  = (const float*)d_in[15];
  const float* Wd1 = (const float*)d_in[16]; const float* bd1 = (const float*)d_in[17];
  const float* Wd2 = (const float*)d_in[18]; const float* bd2 = (const float*)d_in[19];
  const float* Wd3 = (const float*)d_in[20]; const float* bd3 = (const float*)d_in[21];

  float* ws = (float*)d_ws;
  // float-offset workspace map (within the 25,165,824-float budget):
  float* c1   = ws;                         // [0, 16.78M)   conv1 out
  float* c2   = ws + 16777216;              // [16.78M, 25.17M) conv2 out
  float* c3   = ws;                         // reuse (c1 dead) conv3 out
  float* node = ws + 4194304;               // 2,097,152
  float* mo   = ws + 6291456;               // 32,768 (mean per b,t)
  float* gx   = ws + 8388608;               // 2,097,152 fp32
  unsigned short* Abf  = (unsigned short*)(ws + 10485760);  // 512*4096 bf16
  unsigned short* A2bf = (unsigned short*)(ws + 11534336);  // 512*4096 bf16
  unsigned short* WTh  = (unsigned short*)(ws + 12582912);  // 3*4096 bf16
  unsigned short* WTl  = (unsigned short*)(ws + 12589056);  // 3*4096 bf16
  float* out  = (float*)d_out;

  conv1_k<<<512, 256, 0, stream>>>(frames, Wc1, bc1, c1);
  conv2_k<<<512, 256, 0, stream>>>(c1, Wc2, bc2, c2);
  conv3_k<<<512, 256, 0, stream>>>(c2, Wc3, bc3, c3);
  embed_k<<<512, 256, 0, stream>>>(c3, We, be, node);
  wsplit_k<<<48, 256, 0, stream>>>(Wh, WTh, WTl);
  prep_k <<<512, 256, 0, stream>>>(adj, node, Wx, Abf, A2bf, gx);
  seq2_k <<<8,   512, 0, stream>>>(Abf, A2bf, gx, h0, WTh, WTl, bg, tau, Ap, mo, out);
  dec_k  <<<512, 128, 0, stream>>>(mo, Wd1, bd1, Wd2, bd2, Wd3, bd3, out);
}